// Round 10
// baseline (395.742 us; speedup 1.0000x reference)
//
#include <hip/hip_runtime.h>
#include <hip/hip_bf16.h>
#include <stdint.h>

// ---------------------------------------------------------------------------
// STE ternary linear: out = x @ q^T, q = ternary(weight, thr=0.05*mean|w|)
// x: [8192, 4096] fp32, weight: [4096, 4096] fp32, out: [8192, 4096] fp32
//
// R4 i8 m97: 165us. R5 8-phase 256^2: 144us. R8 1-barrier: 136.6us (45%).
// R9 BK=64 3-buf: 138us, conflicts 1.26e7 -> 64B LDS rows conflict under all
//     swizzles tried; 128B rows + (lane&7)-XOR = proven zero. Sink-robust
//     waits bought nothing -> NOT latency-bound.
// MODEL (closes on all 4 kernels): LDS-read BW-bound. Per CU-tile the 8
//     waves read A-panels 4x redundant + B 2x = 192KB; at 85 B/cyc (m134
//     b128) = 2260 cyc floor vs MFMA floor 1305; measured 2562 = 88% of the
//     overlap bound. Sync structure cannot fix traffic.
// R10: B never touches LDS. quant writes qbT in blocked-16 frag-native
//     layout [n>>4][k>>4][n&15][k&15] -> B-frag = one coalesced 1KB
//     global_load_dwordx4 per (ni,kk), L2-resident (2MB/XCD, same-bn blocks
//     share XCD naturally). bf double-buffered IN PLACE (loaded at loop
//     bottom into dead regs, flies across barrier; no VGPR growth). LDS =
//     A only, 3 bufs x 32KB, 128B rows + R8 swizzle, stage t+2 mid-tile,
//     counted vmcnt(8) retires A-stages. New floors: LDS 1500, VMEM ~1600,
//     MFMA 2611 binding. Predicted: gemm 85-100us, MfmaUtil 60-75%,
//     conflicts ~0, FETCH ~150MB, total ~335-355us.
// R11: resubmit of R10 — infra failure #5 of 10 ("container failed twice");
//     all prior ones resolved on identical resubmission. Audit clean:
//     uniform barriers, satisfiable waits, qbT bounds exact, buffer-hazard
//     ledger verified (A(t+1) landed before its barrier; B flies across).
// ---------------------------------------------------------------------------

typedef __attribute__((ext_vector_type(4))) int i32x4;

#define KDIM 4096
#define NDIM 4096

#define M_ROWS 8192     // x rows (blocks 0..M_ROWS-1 in prep)
#define ABS_BLOCKS 1024 // w abs-mean blocks

__device__ inline void gld_lds16(const void* g, void* l) {
  // 16B per lane, LDS dest = wave-uniform base + lane*16
  __builtin_amdgcn_global_load_lds(
      (__attribute__((address_space(1))) void*)g,
      (__attribute__((address_space(3))) void*)l,
      16, 0, 0);
}

__device__ inline int pack4(int a, int b, int c, int d) {
  return (a & 255) | ((b & 255) << 8) | ((c & 255) << 16) | (d << 24);
}

__device__ inline int q8(float v, float inv) {
  int q = __float2int_rn(v * inv);
  return q > 127 ? 127 : (q < -127 ? -127 : q);
}

// ---------------- fused prep: per-row x quant || w abs-mean -----------------
__global__ __launch_bounds__(256) void prep_kernel(
    const float4* __restrict__ x, signed char* __restrict__ xq,
    float* __restrict__ steps, const float4* __restrict__ w, int wn4,
    double* __restrict__ sum) {
  if (blockIdx.x < M_ROWS) {
    const int row = blockIdx.x;
    const float4* xr = x + (size_t)row * 1024;  // 4096 floats = 1024 float4
    float4 v[4];
    float amax = 0.0f;
#pragma unroll
    for (int j = 0; j < 4; ++j) {
      v[j] = xr[threadIdx.x + 256 * j];
      amax = fmaxf(amax, fmaxf(fmaxf(fabsf(v[j].x), fabsf(v[j].y)),
                               fmaxf(fabsf(v[j].z), fabsf(v[j].w))));
    }
#pragma unroll
    for (int off = 32; off > 0; off >>= 1)
      amax = fmaxf(amax, __shfl_down(amax, off, 64));
    __shared__ float wmax[4];
    const int lane = threadIdx.x & 63, wave = threadIdx.x >> 6;
    if (lane == 0) wmax[wave] = amax;
    __syncthreads();
    const float m = fmaxf(fmaxf(wmax[0], wmax[1]), fmaxf(wmax[2], wmax[3]));
    const float inv = m > 0.0f ? 127.0f / m : 0.0f;
    if (threadIdx.x == 0) steps[row] = m > 0.0f ? m / 127.0f : 0.0f;
    int* out = (int*)(xq + (size_t)row * 4096);
#pragma unroll
    for (int j = 0; j < 4; ++j) {
      out[threadIdx.x + 256 * j] = pack4(q8(v[j].x, inv), q8(v[j].y, inv),
                                         q8(v[j].z, inv), q8(v[j].w, inv));
    }
  } else {
    double s = 0.0;
    const int stride = ABS_BLOCKS * 256;
    for (int i = (blockIdx.x - M_ROWS) * 256 + threadIdx.x; i < wn4;
         i += stride) {
      float4 v = w[i];
      s += (double)((fabsf(v.x) + fabsf(v.y)) + (fabsf(v.z) + fabsf(v.w)));
    }
#pragma unroll
    for (int off = 32; off > 0; off >>= 1) s += __shfl_down(s, off, 64);
    __shared__ double wsum[4];
    const int lane = threadIdx.x & 63, wave = threadIdx.x >> 6;
    if (lane == 0) wsum[wave] = s;
    __syncthreads();
    if (threadIdx.x == 0) atomicAdd(sum, wsum[0] + wsum[1] + wsum[2] + wsum[3]);
  }
}

// ------- ternary quantize weight -> i8 in blocked-16 frag-native layout -----
// qbT byte(n,k) at (n>>4)*65536 + (k>>4)*256 + (n&15)*16 + (k&15).
// A 16x16x64 B-frag (ni,kk) of tile t is then the contiguous 1KB at
// ((bn+wn)>>4 + ni)*65536 + (t*8 + kk*4)*256 + lane*16.
__global__ __launch_bounds__(256) void quant_kernel(
    const float4* __restrict__ w, const double* __restrict__ sum,
    signed char* __restrict__ qt, int n4, double inv_n) {
  const float thr = (float)(0.05 * (*sum) * inv_n);
  const int stride = gridDim.x * blockDim.x;
  for (int i = blockIdx.x * blockDim.x + threadIdx.x; i < n4; i += stride) {
    float4 v = w[i];
    int a = v.x > thr ? 1 : (v.x < -thr ? -1 : 0);
    int b = v.y > thr ? 1 : (v.y < -thr ? -1 : 0);
    int c = v.z > thr ? 1 : (v.z < -thr ? -1 : 0);
    int d = v.w > thr ? 1 : (v.w < -thr ? -1 : 0);
    const int n = i >> 10;          // 1024 float4 per row of K=4096
    const int k0 = (i & 1023) * 4;  // k0..k0+3, same 16B chunk (k0 % 4 == 0)
    *(int*)(qt + (size_t)(n >> 4) * 65536 + (k0 >> 4) * 256 + (n & 15) * 16 +
            (k0 & 15)) = pack4(a, b, c, d);
  }
}

// -------- i8 GEMM, 256^2, A-only LDS (3 buf), B direct from L2 --------------
// A: [M][4096] i8; qbT blocked-16; C = i32acc * steps[m].
// 512 thr = 8 waves (2M x 4N); per-wave out 128x64 = acc[8][4] i32x4.
// LDS: A only, 3 bufs x 32KB = 96KB, 128B rows + R8-proven XOR swizzle
// (the only conflict-free config: R4/R9 64B rows -> 1.3-1.7e7 conflicts).
// Per tile t (BK=128): af0 ds-reads; MFMA k0 m0-3 (bf from prev tile);
// stage A(t+2)->buf (t+2)%3 [last read at t-1, barrier-protected]; af1;
// MFMA k0 m4-7 + k1; reload bf = B(t+1) in place (regs dead after k1);
// vmcnt(8) retires A-stages (queue [A4][B8]); barrier; sched_barrier.
// B loads fly across the barrier; compiler waits bf at next-tile use.
#define MFMA_I8 __builtin_amdgcn_mfma_i32_16x16x64_i8

__global__ __launch_bounds__(512, 2) void gemm_i8_bd(
    const signed char* __restrict__ A, const signed char* __restrict__ qbT,
    const float* __restrict__ steps, float* __restrict__ C) {
  __shared__ unsigned char ldsA[98304];  // 3 x 32KB, A only

  const int tid = threadIdx.x;
  const int lane = tid & 63;
  const int w = tid >> 6;

  const int bm = blockIdx.y * 256;
  const int bn = blockIdx.x * 256;

  // ---- A staging (R8-proven): wave w rows w*8+rL (+{0,64,128,192}) ----
  const int rL = lane >> 3;
  const int csw = (((lane & 7) ^ rL) << 4);  // inverse-swizzled source col
  const signed char* aBase = A + (size_t)(bm + w * 8 + rL) * KDIM + csw;
  const int sb = w * 1024;  // LDS chunk base (+lane*16 implicit in gld_lds)

  // ---- A fragment reads (R8-proven) ----
  const int fr = lane & 15;
  const int fk = (lane >> 4) * 16;
  const int xr = (lane & 7) << 4;
  const int cc0 = fk ^ xr;
  const int cc1 = (64 + fk) ^ xr;
  const int wm = (w >> 2) * 128;
  const int wn = (w & 3) * 64;
  const int aro = (wm + fr) * 128;

  // ---- B direct: per-(ni,kk) frag = 1KB coalesced at qbW + off ----
  const signed char* qbW = qbT + (size_t)((bn + wn) >> 4) * 65536 + lane * 16;

  i32x4 acc[8][4] = {};
  i32x4 bf[4][2];

  // ---- prologue: stage A(0)->buf0, A(1)->buf1; load B(0); barrier ----
  {
    gld_lds16(aBase, ldsA + sb);
    gld_lds16(aBase + (size_t)64 * KDIM, ldsA + 8192 + sb);
    gld_lds16(aBase + (size_t)128 * KDIM, ldsA + 16384 + sb);
    gld_lds16(aBase + (size_t)192 * KDIM, ldsA + 24576 + sb);
    const signed char* a1 = aBase + 128;
    gld_lds16(a1, ldsA + 32768 + sb);
    gld_lds16(a1 + (size_t)64 * KDIM, ldsA + 32768 + 8192 + sb);
    gld_lds16(a1 + (size_t)128 * KDIM, ldsA + 32768 + 16384 + sb);
    gld_lds16(a1 + (size_t)192 * KDIM, ldsA + 32768 + 24576 + sb);
#pragma unroll
    for (int ni = 0; ni < 4; ++ni)
#pragma unroll
      for (int kk = 0; kk < 2; ++kk)
        bf[ni][kk] = *(const i32x4*)(qbW + ni * 65536 + kk * 1024);
    asm volatile("s_waitcnt vmcnt(12)" ::: "memory");  // A(0) landed
    __builtin_amdgcn_s_barrier();
    __builtin_amdgcn_sched_barrier(0);
  }

#pragma unroll 1
  for (int t = 0; t < 32; ++t) {
    const unsigned char* Ab = (const unsigned char*)ldsA + (t % 3) * 32768;
    i32x4 af0[8], af1[8];
#pragma unroll
    for (int m = 0; m < 8; ++m)
      af0[m] = *(const i32x4*)(Ab + aro + m * 2048 + cc0);

    // --- MFMA k0 m0-3 (bf loaded a full tile ago -> any wait is cheap) ---
    __builtin_amdgcn_s_setprio(1);
#pragma unroll
    for (int m = 0; m < 4; ++m)
#pragma unroll
      for (int ni = 0; ni < 4; ++ni)
        acc[m][ni] = MFMA_I8(af0[m], bf[ni][0], acc[m][ni], 0, 0, 0);
    __builtin_amdgcn_s_setprio(0);

    // --- stage A(t+2) mid-tile (its buf's reads ended at t-1's barrier) ---
    if (t + 2 < 32) {
      unsigned char* An = (unsigned char*)ldsA + ((t + 2) % 3) * 32768;
      const signed char* aS = aBase + (size_t)(t + 2) * 128;
      gld_lds16(aS, An + sb);
      gld_lds16(aS + (size_t)64 * KDIM, An + 8192 + sb);
      gld_lds16(aS + (size_t)128 * KDIM, An + 16384 + sb);
      gld_lds16(aS + (size_t)192 * KDIM, An + 24576 + sb);
    }

#pragma unroll
    for (int m = 0; m < 8; ++m)
      af1[m] = *(const i32x4*)(Ab + aro + m * 2048 + cc1);

    __builtin_amdgcn_s_setprio(1);
#pragma unroll
    for (int m = 4; m < 8; ++m)
#pragma unroll
      for (int ni = 0; ni < 4; ++ni)
        acc[m][ni] = MFMA_I8(af0[m], bf[ni][0], acc[m][ni], 0, 0, 0);
#pragma unroll
    for (int m = 0; m < 8; ++m)
#pragma unroll
      for (int ni = 0; ni < 4; ++ni)
        acc[m][ni] = MFMA_I8(af1[m], bf[ni][1], acc[m][ni], 0, 0, 0);
    __builtin_amdgcn_s_setprio(0);

    // --- reload bf = B(t+1) in place (bf dead after k1; no VGPR growth) ---
    if (t + 1 < 32) {
#pragma unroll
      for (int ni = 0; ni < 4; ++ni)
#pragma unroll
        for (int kk = 0; kk < 2; ++kk)
          bf[ni][kk] = *(const i32x4*)(qbW + ni * 65536 + (t + 1) * 2048 +
                                       kk * 1024);
      // queue: [A-stage(t+2) 4][B(t+1) 8] -> vmcnt(8) retires A-stages only
      asm volatile("s_waitcnt vmcnt(8)" ::: "memory");
      __builtin_amdgcn_s_barrier();
      __builtin_amdgcn_sched_barrier(0);
    }
  }

  // ---- epilogue: out = i32acc * steps[m] (proven) ----
  const int cn = lane & 15;
  const int cm = (lane >> 4) * 4;
  float stp[8][4];
#pragma unroll
  for (int mi = 0; mi < 8; ++mi)
#pragma unroll
    for (int r = 0; r < 4; ++r)
      stp[mi][r] = steps[bm + wm + mi * 16 + cm + r];
#pragma unroll
  for (int mi = 0; mi < 8; ++mi) {
#pragma unroll
    for (int ni = 0; ni < 4; ++ni) {
#pragma unroll
      for (int r = 0; r < 4; ++r) {
        const int m = bm + wm + mi * 16 + cm + r;
        const int n = bn + wn + ni * 16 + cn;
        C[(size_t)m * NDIM + n] = (float)acc[mi][ni][r] * stp[mi][r];
      }
    }
  }
}

// ---------------------------------------------------------------------------
extern "C" void kernel_launch(void* const* d_in, const int* in_sizes, int n_in,
                              void* d_out, int out_size, void* d_ws,
                              size_t ws_size, hipStream_t stream) {
  const float* x = (const float*)d_in[0];
  const float* w = (const float*)d_in[1];
  float* out = (float*)d_out;

  const int K = 4096;
  const int N = 4096;
  const int NW = in_sizes[1];      // 4096*4096

  char* ws = (char*)d_ws;
  double* d_sum = (double*)ws;                               // 8 B
  float* steps = (float*)(ws + 256);                         // M floats (32 KB)
  signed char* qb = (signed char*)(ws + 65536);              // N*K i8 (16.8 MB)
  signed char* xq = qb + (size_t)N * K;                      // M*K i8 (33.6 MB)

  hipMemsetAsync(d_sum, 0, sizeof(double), stream);
  prep_kernel<<<M_ROWS + ABS_BLOCKS, 256, 0, stream>>>(
      (const float4*)x, xq, steps, (const float4*)w, NW / 4, d_sum);
  quant_kernel<<<2048, 256, 0, stream>>>((const float4*)w, d_sum, qb, NW / 4,
                                         1.0 / NW);
  dim3 grid(N / 256, M_ROWS / 256);
  gemm_i8_bd<<<grid, 512, 0, stream>>>(xq, qb, steps, out);
}